// Round 8
// baseline (428.128 us; speedup 1.0000x reference)
//
#include <hip/hip_runtime.h>
#include <math.h>

#define D 64

// ---------------- K1: zero the packed count/degree array ----------------

__global__ void k_zero(unsigned long long* packed, int n) {
    int i = blockIdx.x * 256 + threadIdx.x;
    if (i < n) packed[i] = 0ull;
}

// ---------------- K2: edge count (one u64 atomic) + mm1, block-range split ----------------
// packed[c] += (1<<48) | round(ew * 2^32).  Per-node: count < 2^16, wsum < 2^38 -> carry-free.
// mm1: one wave per row, W1 column in 64 VGPRs, x row via wave-uniform float4 broadcasts.

__global__ void __launch_bounds__(256) k_count_mm1(
        const int* __restrict__ col, const float* __restrict__ ew,
        unsigned long long* __restrict__ packed, int E, int cntBlocks,
        const float* __restrict__ X, const float* __restrict__ W1,
        float* __restrict__ Y, int n) {
    if (blockIdx.x < cntBlocks) {
        int e = blockIdx.x * 256 + threadIdx.x;
        if (e < E) {
            unsigned long long add = (1ull << 48) |
                (unsigned long long)(ew[e] * 4294967296.0f + 0.5f);
            atomicAdd(&packed[col[e]], add);
        }
    } else {
        int lane = threadIdx.x & 63;
        float wreg[64];
#pragma unroll
        for (int k = 0; k < 64; ++k) wreg[k] = W1[k * 64 + lane];  // coalesced per k
        int wv  = (blockIdx.x - cntBlocks) * 4 + (threadIdx.x >> 6);
        int nwv = (gridDim.x - cntBlocks) * 4;
        const float4* x4 = (const float4*)X;
        for (int r = wv; r < n; r += nwv) {
            float acc = 0.f;
#pragma unroll
            for (int j = 0; j < 16; ++j) {
                float4 v = x4[r * 16 + j];   // wave-uniform address -> broadcast
                acc += v.x * wreg[4 * j + 0] + v.y * wreg[4 * j + 1]
                     + v.z * wreg[4 * j + 2] + v.w * wreg[4 * j + 3];
            }
            Y[r * 64 + lane] = acc;
        }
    }
}

// ---------------- K3: dinv (all blocks) + exclusive scan -> rowptr (block 0) ----------------

__global__ void k_dinv_scan(const unsigned long long* __restrict__ packed,
                            float* __restrict__ dinv, int* __restrict__ rowptr, int n) {
    int i = blockIdx.x * 256 + threadIdx.x;
    if (i < n) {
        unsigned long long v = packed[i];
        float deg = 1.0f + (float)((double)(v & 0x0000FFFFFFFFFFFFull) * (1.0 / 4294967296.0));
        dinv[i] = rsqrtf(deg);   // deg >= 1 (self-loop); quantization ~1e-8
    }
    if (blockIdx.x == 0) {
        __shared__ int wscr[4];
        int t = threadIdx.x, lane = t & 63, wave = t >> 6;
        int base = 0;
        int ntiles = (n + 1023) >> 10;
        for (int tile = 0; tile < ntiles; ++tile) {
            int i0 = (tile << 10) + t * 4;
            int c0 = (i0 + 0 < n) ? (int)(packed[i0 + 0] >> 48) : 0;
            int c1 = (i0 + 1 < n) ? (int)(packed[i0 + 1] >> 48) : 0;
            int c2 = (i0 + 2 < n) ? (int)(packed[i0 + 2] >> 48) : 0;
            int c3 = (i0 + 3 < n) ? (int)(packed[i0 + 3] >> 48) : 0;
            int s = c0 + c1 + c2 + c3, incl = s;
#pragma unroll
            for (int off = 1; off < 64; off <<= 1) {
                int u = __shfl_up(incl, off, 64);
                if (lane >= off) incl += u;
            }
            if (lane == 63) wscr[wave] = incl;
            __syncthreads();
            int wpre = 0, tot = 0;
#pragma unroll
            for (int w = 0; w < 4; ++w) { int v = wscr[w]; if (w < wave) wpre += v; tot += v; }
            int ex = base + wpre + (incl - s);
            if (i0 + 0 < n) rowptr[i0 + 0] = ex;
            if (i0 + 1 < n) rowptr[i0 + 1] = ex + c0;
            if (i0 + 2 < n) rowptr[i0 + 2] = ex + c0 + c1;
            if (i0 + 3 < n) rowptr[i0 + 3] = ex + c0 + c1 + c2;
            base += tot;
            __syncthreads();
        }
        // post-fill convention: segment c = [rowptr[c-1], rowptr[c])
    }
}

// ---------------- K4: CSR fill (weight = dinv[row]*ew; dinv[col] folded at gather) ----------------

__global__ void k_fill(const int* __restrict__ row, const int* __restrict__ col,
                       const float* __restrict__ ew, const float* __restrict__ dinv,
                       int* rowptr, int2* __restrict__ edges, int E) {
    int e = blockIdx.x * 256 + threadIdx.x;
    if (e < E) {
        int r = row[e];
        float wv = dinv[r] * ew[e];
        int p = atomicAdd(&rowptr[col[e]], 1);
        edges[p] = make_int2(r, __float_as_int(wv));
    }
}

// ---------------- per-node aggregate (wave-wide, lane = feature) ----------------
// returns dinv[c] * ( dinv[c]*xw[c] + sum_e (dinv[r]*ew)*xw[r] ) + b

__device__ __forceinline__ float gather_node(const float* __restrict__ xw,
                                             const int* __restrict__ rowptr,
                                             const int2* __restrict__ edges,
                                             float d, float bb, int node, int lane) {
    float acc0 = d * xw[node * 64 + lane];   // self-loop
    float acc1 = 0.f, acc2 = 0.f, acc3 = 0.f;
    int p  = (node == 0) ? 0 : rowptr[node - 1];
    int pe = rowptr[node];
    for (; p + 4 <= pe; p += 4) {
        int2 e0 = edges[p + 0];
        int2 e1 = edges[p + 1];
        int2 e2 = edges[p + 2];
        int2 e3 = edges[p + 3];
        acc0 += __int_as_float(e0.y) * xw[e0.x * 64 + lane];
        acc1 += __int_as_float(e1.y) * xw[e1.x * 64 + lane];
        acc2 += __int_as_float(e2.y) * xw[e2.x * 64 + lane];
        acc3 += __int_as_float(e3.y) * xw[e3.x * 64 + lane];
    }
    for (; p < pe; ++p) {
        int2 e = edges[p];
        acc0 += __int_as_float(e.y) * xw[e.x * 64 + lane];
    }
    return d * ((acc0 + acc1) + (acc2 + acc3)) + bb;
}

// ---------------- K5: conv1 aggregate + relu + @W2 (register W, shfl matmul, no LDS) ----------------

__global__ void k_gather_mm(const float* __restrict__ xw, const float* __restrict__ dinv,
                            const float* __restrict__ b, const int* __restrict__ rowptr,
                            const int2* __restrict__ edges, const float* __restrict__ W,
                            float* __restrict__ out, int n) {
    int lane = threadIdx.x & 63;
    float wreg[64];
#pragma unroll
    for (int k = 0; k < 64; ++k) wreg[k] = W[k * 64 + lane];
    float bb = b[lane];
    int wv  = blockIdx.x * 4 + (threadIdx.x >> 6);
    int nwv = gridDim.x * 4;
    for (int node = wv; node < n; node += nwv) {
        float h = fmaxf(gather_node(xw, rowptr, edges, dinv[node], bb, node, lane), 0.0f);
        float s = 0.f;
#pragma unroll
        for (int k = 0; k < 64; ++k) s += __shfl(h, k, 64) * wreg[k];
        out[node * 64 + lane] = s;
    }
}

// ---------------- K6: conv2 aggregate + relu + MLP head + sigmoid (register weights) ----------------
// Wm1 column in 64 VGPRs; Wm2 split by k-quarter (16 VGPRs/lane) + shfl_xor reduction.

__global__ void k_gather_head(const float* __restrict__ xw, const float* __restrict__ dinv,
                              const float* __restrict__ b, const int* __restrict__ rowptr,
                              const int2* __restrict__ edges,
                              const float* __restrict__ Wm1, const float* __restrict__ bm1,
                              const float* __restrict__ Wm2, const float* __restrict__ bm2,
                              float* __restrict__ out, int n) {
    int lane = threadIdx.x & 63;
    int q = lane >> 4, c16 = lane & 15;
    float w1reg[64];
#pragma unroll
    for (int k = 0; k < 64; ++k) w1reg[k] = Wm1[k * 64 + lane];
    float w2reg[16];
#pragma unroll
    for (int j = 0; j < 16; ++j) w2reg[j] = Wm2[(q * 16 + j) * 16 + c16];
    float bb = b[lane];
    float sb1 = bm1[lane];
    float sb2 = bm2[c16];
    int wv  = blockIdx.x * 4 + (threadIdx.x >> 6);
    int nwv = gridDim.x * 4;
    for (int node = wv; node < n; node += nwv) {
        float h2 = fmaxf(gather_node(xw, rowptr, edges, dinv[node], bb, node, lane), 0.0f);
        // h3[lane] = relu(sum_k h2[k] * Wm1[k][lane] + bm1[lane])
        float s = sb1;
#pragma unroll
        for (int k = 0; k < 64; ++k) s += __shfl(h2, k, 64) * w1reg[k];
        float h3 = fmaxf(s, 0.0f);
        // logits: lane computes partial over its k-quarter for col c16, then xor-reduce
        float p = 0.f;
#pragma unroll
        for (int j = 0; j < 16; ++j) p += __shfl(h3, q * 16 + j, 64) * w2reg[j];
        p += __shfl_xor(p, 32, 64);
        p += __shfl_xor(p, 16, 64);
        if (lane < 16) out[node * 16 + lane] = 1.0f / (1.0f + expf(-(sb2 + p)));
    }
}

// ---------------- launch ----------------

extern "C" void kernel_launch(void* const* d_in, const int* in_sizes, int n_in,
                              void* d_out, int out_size, void* d_ws, size_t ws_size,
                              hipStream_t stream) {
    const float* x   = (const float*)d_in[0];
    const int*   ei  = (const int*)d_in[1];
    const float* ew  = (const float*)d_in[2];
    const float* W1  = (const float*)d_in[3];
    const float* b1  = (const float*)d_in[4];
    const float* W2  = (const float*)d_in[5];
    const float* b2  = (const float*)d_in[6];
    const float* Wm1 = (const float*)d_in[7];
    const float* bm1 = (const float*)d_in[8];
    const float* Wm2 = (const float*)d_in[9];
    const float* bm2 = (const float*)d_in[10];

    int n = in_sizes[0] / D;     // 50000
    int E = in_sizes[1] / 2;     // 800000
    const int* row = ei;
    const int* col = ei + E;

    // workspace layout (all segment sizes multiples of 16 B)
    char* wsb = (char*)d_ws;
    unsigned long long* packed = (unsigned long long*)wsb;   // n * 8 B
    int2*  edges  = (int2*)(packed + n);                     // E * 8 B
    float* xw1    = (float*)(edges + E);                     // n*64 f
    float* xw2    = xw1 + (size_t)n * D;                     // n*64 f
    float* dinv   = xw2 + (size_t)n * D;                     // n f
    int*   rowptr = (int*)(dinv + n);                        // n i
    float* outp   = (float*)d_out;

    int gN = (n + 255) / 256;
    int gE = (E + 255) / 256;
    int mmBlocks = 1024;

    // K1: zero packed
    k_zero<<<gN, 256, 0, stream>>>(packed, n);
    // K2: edge count (u64 packed) + mm1 (xw1 = x @ W1), block-range split
    k_count_mm1<<<gE + mmBlocks, 256, 0, stream>>>(col, ew, packed, E, gE, x, W1, xw1, n);
    // K3: dinv + single-block scan -> rowptr
    k_dinv_scan<<<gN, 256, 0, stream>>>(packed, dinv, rowptr, n);
    // K4: CSR fill
    k_fill<<<gE, 256, 0, stream>>>(row, col, ew, dinv, rowptr, edges, E);
    // K5: conv1 aggregate + relu + @W2 -> xw2
    k_gather_mm<<<2048, 256, 0, stream>>>(xw1, dinv, b1, rowptr, edges, W2, xw2, n);
    // K6: conv2 aggregate + relu + MLP head + sigmoid -> out
    k_gather_head<<<2048, 256, 0, stream>>>(xw2, dinv, b2, rowptr, edges,
                                            Wm1, bm1, Wm2, bm2, outp, n);
}

// Round 9
// 352.955 us; speedup vs baseline: 1.2130x; 1.2130x over previous
//
#include <hip/hip_runtime.h>
#include <hip/hip_fp16.h>
#include <math.h>

#define D 64

// ---------------- K1: zero the packed count/degree array ----------------

__global__ void k_zero(unsigned long long* packed, int n) {
    int i = blockIdx.x * 256 + threadIdx.x;
    if (i < n) packed[i] = 0ull;
}

// ---------------- K2: edge count (one u64 atomic) + mm1, block-range split ----------------
// packed[c] += (1<<48) | round(ew * 2^32).  Per-node: count < 2^16, wsum < 2^38 -> carry-free.
// mm1: one wave per row, W1 column in 64 VGPRs (launch_bounds floor prevents the
// round-8 spill heuristic), x row via wave-uniform float4 broadcasts. Output fp16.

__global__ void __launch_bounds__(256, 2) k_count_mm1(
        const int* __restrict__ col, const float* __restrict__ ew,
        unsigned long long* __restrict__ packed, int E, int cntBlocks,
        const float* __restrict__ X, const float* __restrict__ W1,
        __half* __restrict__ Y, int n) {
    if (blockIdx.x < cntBlocks) {
        int e = blockIdx.x * 256 + threadIdx.x;
        if (e < E) {
            unsigned long long add = (1ull << 48) |
                (unsigned long long)(ew[e] * 4294967296.0f + 0.5f);
            atomicAdd(&packed[col[e]], add);
        }
    } else {
        int lane = threadIdx.x & 63;
        float wreg[64];
#pragma unroll
        for (int k = 0; k < 64; ++k) wreg[k] = W1[k * 64 + lane];  // coalesced per k
        int wv  = (blockIdx.x - cntBlocks) * 4 + (threadIdx.x >> 6);
        int nwv = (gridDim.x - cntBlocks) * 4;
        const float4* x4 = (const float4*)X;
        for (int r = wv; r < n; r += nwv) {
            float acc = 0.f;
#pragma unroll
            for (int j = 0; j < 16; ++j) {
                float4 v = x4[r * 16 + j];   // wave-uniform address -> broadcast
                acc += v.x * wreg[4 * j + 0] + v.y * wreg[4 * j + 1]
                     + v.z * wreg[4 * j + 2] + v.w * wreg[4 * j + 3];
            }
            Y[r * 64 + lane] = __float2half(acc);
        }
    }
}

// ---------------- K3: dinv (all blocks) + exclusive scan -> rowptr (block 0) ----------------

__global__ void k_dinv_scan(const unsigned long long* __restrict__ packed,
                            float* __restrict__ dinv, int* __restrict__ rowptr, int n) {
    int i = blockIdx.x * 256 + threadIdx.x;
    if (i < n) {
        unsigned long long v = packed[i];
        float deg = 1.0f + (float)((double)(v & 0x0000FFFFFFFFFFFFull) * (1.0 / 4294967296.0));
        dinv[i] = rsqrtf(deg);   // deg >= 1 (self-loop); quantization ~1e-8
    }
    if (blockIdx.x == 0) {
        __shared__ int wscr[4];
        int t = threadIdx.x, lane = t & 63, wave = t >> 6;
        int base = 0;
        int ntiles = (n + 1023) >> 10;
        for (int tile = 0; tile < ntiles; ++tile) {
            int i0 = (tile << 10) + t * 4;
            int c0 = (i0 + 0 < n) ? (int)(packed[i0 + 0] >> 48) : 0;
            int c1 = (i0 + 1 < n) ? (int)(packed[i0 + 1] >> 48) : 0;
            int c2 = (i0 + 2 < n) ? (int)(packed[i0 + 2] >> 48) : 0;
            int c3 = (i0 + 3 < n) ? (int)(packed[i0 + 3] >> 48) : 0;
            int s = c0 + c1 + c2 + c3, incl = s;
#pragma unroll
            for (int off = 1; off < 64; off <<= 1) {
                int u = __shfl_up(incl, off, 64);
                if (lane >= off) incl += u;
            }
            if (lane == 63) wscr[wave] = incl;
            __syncthreads();
            int wpre = 0, tot = 0;
#pragma unroll
            for (int w = 0; w < 4; ++w) { int v = wscr[w]; if (w < wave) wpre += v; tot += v; }
            int ex = base + wpre + (incl - s);
            if (i0 + 0 < n) rowptr[i0 + 0] = ex;
            if (i0 + 1 < n) rowptr[i0 + 1] = ex + c0;
            if (i0 + 2 < n) rowptr[i0 + 2] = ex + c0 + c1;
            if (i0 + 3 < n) rowptr[i0 + 3] = ex + c0 + c1 + c2;
            base += tot;
            __syncthreads();
        }
        // post-fill convention: segment c = [rowptr[c-1], rowptr[c])
    }
}

// ---------------- K4: CSR fill (weight = dinv[row]*ew; dinv[col] folded at gather) ----------------

__global__ void k_fill(const int* __restrict__ row, const int* __restrict__ col,
                       const float* __restrict__ ew, const float* __restrict__ dinv,
                       int* rowptr, int2* __restrict__ edges, int E) {
    int e = blockIdx.x * 256 + threadIdx.x;
    if (e < E) {
        int r = row[e];
        float wv = dinv[r] * ew[e];
        int p = atomicAdd(&rowptr[col[e]], 1);
        edges[p] = make_int2(r, __float_as_int(wv));
    }
}

// ---------------- per-node aggregate (wave-wide, lane = feature, fp16 features) ----------------
// returns dinv[c] * ( dinv[c]*xw[c] + sum_e (dinv[r]*ew)*xw[r] ) + b
// 8-deep edge unroll -> 8 outstanding 128B gathers per wave.

__device__ __forceinline__ float gather_node(const __half* __restrict__ xw,
                                             const int* __restrict__ rowptr,
                                             const int2* __restrict__ edges,
                                             float d, float bb, int node, int lane) {
    float acc0 = d * __half2float(xw[node * 64 + lane]);   // self-loop
    float acc1 = 0.f, acc2 = 0.f, acc3 = 0.f;
    int p  = (node == 0) ? 0 : rowptr[node - 1];
    int pe = rowptr[node];
    for (; p + 8 <= pe; p += 8) {
        int2 e0 = edges[p + 0];
        int2 e1 = edges[p + 1];
        int2 e2 = edges[p + 2];
        int2 e3 = edges[p + 3];
        int2 e4 = edges[p + 4];
        int2 e5 = edges[p + 5];
        int2 e6 = edges[p + 6];
        int2 e7 = edges[p + 7];
        float v0 = __half2float(xw[e0.x * 64 + lane]);
        float v1 = __half2float(xw[e1.x * 64 + lane]);
        float v2 = __half2float(xw[e2.x * 64 + lane]);
        float v3 = __half2float(xw[e3.x * 64 + lane]);
        float v4 = __half2float(xw[e4.x * 64 + lane]);
        float v5 = __half2float(xw[e5.x * 64 + lane]);
        float v6 = __half2float(xw[e6.x * 64 + lane]);
        float v7 = __half2float(xw[e7.x * 64 + lane]);
        acc0 += __int_as_float(e0.y) * v0;
        acc1 += __int_as_float(e1.y) * v1;
        acc2 += __int_as_float(e2.y) * v2;
        acc3 += __int_as_float(e3.y) * v3;
        acc0 += __int_as_float(e4.y) * v4;
        acc1 += __int_as_float(e5.y) * v5;
        acc2 += __int_as_float(e6.y) * v6;
        acc3 += __int_as_float(e7.y) * v7;
    }
    for (; p + 4 <= pe; p += 4) {
        int2 e0 = edges[p + 0];
        int2 e1 = edges[p + 1];
        int2 e2 = edges[p + 2];
        int2 e3 = edges[p + 3];
        acc0 += __int_as_float(e0.y) * __half2float(xw[e0.x * 64 + lane]);
        acc1 += __int_as_float(e1.y) * __half2float(xw[e1.x * 64 + lane]);
        acc2 += __int_as_float(e2.y) * __half2float(xw[e2.x * 64 + lane]);
        acc3 += __int_as_float(e3.y) * __half2float(xw[e3.x * 64 + lane]);
    }
    for (; p < pe; ++p) {
        int2 e = edges[p];
        acc0 += __int_as_float(e.y) * __half2float(xw[e.x * 64 + lane]);
    }
    return d * ((acc0 + acc1) + (acc2 + acc3)) + bb;
}

// ---------------- K5: conv1 aggregate + relu + @W2 (LDS-staged W, barriers) ----------------

__global__ void k_gather_mm(const __half* __restrict__ xw, const float* __restrict__ dinv,
                            const float* __restrict__ b, const int* __restrict__ rowptr,
                            const int2* __restrict__ edges, const float* __restrict__ W,
                            __half* __restrict__ out, int n) {
    __shared__ float ws[64][64];
    __shared__ float hs[4][64];
    int tid = threadIdx.x;
    for (int i = tid; i < 4096; i += 256) ws[i >> 6][i & 63] = W[i];

    int lane = tid & 63, w = tid >> 6;
    float bb = b[lane];
    int ngrp = (n + 3) >> 2;
    for (int g = blockIdx.x; g < ngrp; g += gridDim.x) {
        int node = g * 4 + w;
        __syncthreads();  // ws ready (1st) / hs free (later)
        if (node < n)
            hs[w][lane] = fmaxf(gather_node(xw, rowptr, edges, dinv[node], bb, node, lane), 0.0f);
        __syncthreads();  // hs ready
        if (node < n) {
            float s = 0.f;
#pragma unroll
            for (int k = 0; k < 64; ++k) s += hs[w][k] * ws[k][lane];
            out[node * 64 + lane] = __float2half(s);
        }
    }
}

// ---------------- K6: conv2 aggregate + relu + MLP head + sigmoid (LDS weights) ----------------

__global__ void k_gather_head(const __half* __restrict__ xw, const float* __restrict__ dinv,
                              const float* __restrict__ b, const int* __restrict__ rowptr,
                              const int2* __restrict__ edges,
                              const float* __restrict__ Wm1, const float* __restrict__ bm1,
                              const float* __restrict__ Wm2, const float* __restrict__ bm2,
                              float* __restrict__ out, int n) {
    __shared__ float w1[64][64];
    __shared__ float w2[64][16];
    __shared__ float sb1[64];
    __shared__ float sb2[16];
    __shared__ float h2s[4][64];
    __shared__ float h3s[4][64];
    int tid = threadIdx.x;
    for (int i = tid; i < 4096; i += 256) w1[i >> 6][i & 63] = Wm1[i];
    for (int i = tid; i < 1024; i += 256) w2[i >> 4][i & 15] = Wm2[i];
    if (tid < 64) sb1[tid] = bm1[tid];
    if (tid < 16) sb2[tid] = bm2[tid];

    int lane = tid & 63, w = tid >> 6;
    float bb = b[lane];
    int ngrp = (n + 3) >> 2;
    for (int g = blockIdx.x; g < ngrp; g += gridDim.x) {
        int node = g * 4 + w;
        __syncthreads();  // weights ready (1st) / h2s,h3s free (later)
        if (node < n)
            h2s[w][lane] = fmaxf(gather_node(xw, rowptr, edges, dinv[node], bb, node, lane), 0.0f);
        __syncthreads();  // h2s ready
        if (node < n) {
            float s = sb1[lane];
#pragma unroll
            for (int k = 0; k < 64; ++k) s += h2s[w][k] * w1[k][lane];
            h3s[w][lane] = fmaxf(s, 0.0f);
        }
        __syncthreads();  // h3s ready
        if (node < n && lane < 16) {
            float s2 = sb2[lane];
#pragma unroll
            for (int k = 0; k < 64; ++k) s2 += h3s[w][k] * w2[k][lane];
            out[node * 16 + lane] = 1.0f / (1.0f + expf(-s2));
        }
    }
}

// ---------------- launch ----------------

extern "C" void kernel_launch(void* const* d_in, const int* in_sizes, int n_in,
                              void* d_out, int out_size, void* d_ws, size_t ws_size,
                              hipStream_t stream) {
    const float* x   = (const float*)d_in[0];
    const int*   ei  = (const int*)d_in[1];
    const float* ew  = (const float*)d_in[2];
    const float* W1  = (const float*)d_in[3];
    const float* b1  = (const float*)d_in[4];
    const float* W2  = (const float*)d_in[5];
    const float* b2  = (const float*)d_in[6];
    const float* Wm1 = (const float*)d_in[7];
    const float* bm1 = (const float*)d_in[8];
    const float* Wm2 = (const float*)d_in[9];
    const float* bm2 = (const float*)d_in[10];

    int n = in_sizes[0] / D;     // 50000
    int E = in_sizes[1] / 2;     // 800000
    const int* row = ei;
    const int* col = ei + E;

    // workspace layout (all segment sizes multiples of 16 B)
    char* wsb = (char*)d_ws;
    unsigned long long* packed = (unsigned long long*)wsb;   // n * 8 B
    int2*   edges  = (int2*)(packed + n);                    // E * 8 B
    __half* xw1    = (__half*)(edges + E);                   // n*64 h
    __half* xw2    = xw1 + (size_t)n * D;                    // n*64 h
    float*  dinv   = (float*)(xw2 + (size_t)n * D);          // n f
    int*    rowptr = (int*)(dinv + n);                       // n i
    float*  outp   = (float*)d_out;

    int gN = (n + 255) / 256;
    int gE = (E + 255) / 256;
    int mmBlocks = 1024;

    // K1: zero packed
    k_zero<<<gN, 256, 0, stream>>>(packed, n);
    // K2: edge count (u64 packed) + mm1 (xw1 = x @ W1, fp16 out), block-range split
    k_count_mm1<<<gE + mmBlocks, 256, 0, stream>>>(col, ew, packed, E, gE, x, W1, xw1, n);
    // K3: dinv + single-block scan -> rowptr
    k_dinv_scan<<<gN, 256, 0, stream>>>(packed, dinv, rowptr, n);
    // K4: CSR fill
    k_fill<<<gE, 256, 0, stream>>>(row, col, ew, dinv, rowptr, edges, E);
    // K5: conv1 aggregate + relu + @W2 -> xw2 (fp16)
    k_gather_mm<<<2048, 256, 0, stream>>>(xw1, dinv, b1, rowptr, edges, W2, xw2, n);
    // K6: conv2 aggregate + relu + MLP head + sigmoid -> out
    k_gather_head<<<2048, 256, 0, stream>>>(xw2, dinv, b2, rowptr, edges,
                                            Wm1, bm1, Wm2, bm2, outp, n);
}